// Round 8
// baseline (530.612 us; speedup 1.0000x reference)
//
#include <hip/hip_runtime.h>

#define NDIM 128
#define NBASES 8
#define KDIM 1152            // 8*128 (bases) + 128 (root slot)
#define GTILE 8              // nodes per block = waves per block (512 threads)
#define APITCH 1160          // shorts; row stride 2320 B (16B-divisible, >= 2048 stage)

typedef __attribute__((ext_vector_type(8))) __bf16 bfrag;
typedef __attribute__((ext_vector_type(4))) float f32x4;

__device__ __forceinline__ float bf2f(unsigned short b) {
    return __uint_as_float(((unsigned)b) << 16);
}
__device__ __forceinline__ unsigned short f2bf(float f) {
    unsigned u = __float_as_uint(f);
    unsigned r = u + 0x7FFFu + ((u >> 16) & 1u);   // RNE
    return (unsigned short)(r >> 16);
}
__device__ __forceinline__ unsigned pack2bf(float lo, float hi) {
    return (unsigned)f2bf(lo) | ((unsigned)f2bf(hi) << 16);
}
__device__ __forceinline__ float loadF(const void* p, int idx, int isf32) {
    return isf32 ? ((const float*)p)[idx] : bf2f(((const unsigned short*)p)[idx]);
}

// ---------- dtype sniffing (R7-proven ILP version) ----------
__global__ void detect_k(const unsigned short* __restrict__ xs,
                         const int* __restrict__ ei, int* __restrict__ meta) {
    if (threadIdx.x != 0 || blockIdx.x != 0) return;
    const uint4* xv = (const uint4*)xs;
    unsigned f32m = 0;
    uint4 bx[16];
    #pragma unroll
    for (int i = 0; i < 16; ++i) bx[i] = xv[i];
    #pragma unroll
    for (int i = 0; i < 16; ++i) {
        unsigned a = bx[i].x, b = bx[i].y, c = bx[i].z, d = bx[i].w;
        f32m |= (((a & 0xFFFFu) >> 7) & 0xFFu) > 124u;
        f32m |= (((b & 0xFFFFu) >> 7) & 0xFFu) > 124u;
        f32m |= (((c & 0xFFFFu) >> 7) & 0xFFu) > 124u;
        f32m |= (((d & 0xFFFFu) >> 7) & 0xFFu) > 124u;
    }
    const uint4* ev = (const uint4*)ei;
    unsigned nzm = 0;
    for (int r = 0; r < 4; ++r) {
        uint4 be[16];
        #pragma unroll
        for (int i = 0; i < 16; ++i) be[i] = ev[r * 16 + i];
        #pragma unroll
        for (int i = 0; i < 16; ++i) nzm |= be[i].y | be[i].w;
    }
    meta[0] = f32m ? 1 : 0;
    meta[1] = nzm ? 0 : 1;
}

// merged: BT build + special-embedding copy + dst-histogram (R9-proven)
__global__ void misc_k(const void* __restrict__ basis, const void* __restrict__ root,
                       const void* __restrict__ se, const int* __restrict__ meta,
                       unsigned short* __restrict__ BT, void* __restrict__ out,
                       int scount, int sbase,
                       const int* __restrict__ ei, int E, int N, int* __restrict__ hist) {
    int t = blockIdx.x * 256 + threadIdx.x;
    int isf32 = meta[0];
    if (t < NDIM * KDIM) {
        int j = t / KDIM, k = t % KDIM;
        float v = (k < NBASES * NDIM) ? loadF(basis, k * NDIM + j, isf32)
                                      : loadF(root, (k - NBASES * NDIM) * NDIM + j, isf32);
        BT[t] = f2bf(v);
    } else {
        int u = t - NDIM * KDIM;
        if (u < scount) {
            float v = loadF(se, u, isf32);
            if (isf32) ((float*)out)[sbase + u] = v;
            else       ((unsigned short*)out)[sbase + u] = f2bf(v);
        } else {
            int e = u - scount;
            if (e < E) {
                int dst = meta[1] ? ei[2 * (E + e)] : ei[E + e];
                dst = min(max(dst, 0), N - 1);
                atomicAdd(&hist[dst], 1);
            }
        }
    }
}

// ---------- hierarchical exclusive scan (R9-proven: consumers add bpre) ----------
__global__ void scanA_k(const int* __restrict__ hist, int N,
                        int* __restrict__ offsets, int* __restrict__ bsum) {
    __shared__ int s[1024];
    int tid = threadIdx.x;
    int idx = blockIdx.x * 1024 + tid;
    int v = (idx < N) ? hist[idx] : 0;
    s[tid] = v;
    __syncthreads();
    for (int off = 1; off < 1024; off <<= 1) {
        int t = 0;
        if (tid >= off) t = s[tid - off];
        __syncthreads();
        if (tid >= off) s[tid] += t;
        __syncthreads();
    }
    if (idx < N) offsets[idx] = s[tid] - v;           // exclusive within block
    if (tid == 1023) bsum[blockIdx.x] = s[1023];
}
__global__ void scanB_k(const int* __restrict__ bsum, int NB, int N,
                        int* __restrict__ bpre, int* __restrict__ offsets) {
    __shared__ int s[64];
    int tid = threadIdx.x;
    int v = (tid < NB) ? bsum[tid] : 0;
    s[tid] = v;
    __syncthreads();
    for (int off = 1; off < 64; off <<= 1) {
        int t = 0;
        if (tid >= off) t = s[tid - off];
        __syncthreads();
        if (tid >= off) s[tid] += t;
        __syncthreads();
    }
    if (tid < NB) bpre[tid] = s[tid] - v;
    if (tid == NB - 1) offsets[N] = s[tid];           // grand total (absolute)
}

__global__ void scatter_k(const int* __restrict__ ei, const int* __restrict__ et,
                          int E, int N, const int* __restrict__ meta,
                          const int* __restrict__ offsets, const int* __restrict__ bpre,
                          int* __restrict__ cursor, int* __restrict__ sorted) {
    int e = blockIdx.x * 256 + threadIdx.x;
    if (e >= E) return;
    int i64 = meta[1];
    int src = i64 ? ei[2 * e] : ei[e];
    int dst = i64 ? ei[2 * (E + e)] : ei[E + e];
    int rel = i64 ? et[2 * e] : et[e];
    src = min(max(src, 0), N - 1);
    dst = min(max(dst, 0), N - 1);
    rel = rel & 63;
    int pos = offsets[dst] + bpre[dst >> 10] + atomicAdd(&cursor[dst], 1);
    sorted[pos] = src | (rel << 16);
}

// ---------- main fused kernel ----------
// R15 == R14 resubmission (round-7 failure was container-level, no diagnostics;
// kernel audited for hang/fault — none found).
// (1) async gather: global_load_lds stages one 256B bf16 row per instruction
// (64 lanes x 4B, zero VGPR cost) into per-wave LDS; edges issued in chunks
// of 8 (padded with row-0 dummies so vmcnt immediates are constant),
// double-buffered between stage_lds and the wave's own A_lds row (written
// only in the epilogue, after the final vmcnt(0) drain). Up to 16 loads in
// flight per wave vs 2 before. vmcnt(8) accounting is sound: no other VMEM
// ops between issue and wait (consume is LDS/VALU only).
// (2) GTILE 16->8: 512-thread blocks, 38.0KB LDS -> 4 blocks/CU (32-wave
// ceiling); Phase B uses ALL 8 waves (16 cols each, A rows 8-15 duplicated
// via m&7, rows>=8 discarded at store).
// Consume arithmetic + epilogue + f32 fallback = R13 verbatim.
__global__ __launch_bounds__(512, 8) void rgcn_main_k(
    const void* __restrict__ x, const void* __restrict__ comp,
    const void* __restrict__ bias, const unsigned short* __restrict__ BT,
    const int* __restrict__ meta, const int* __restrict__ offsets,
    const int* __restrict__ bpre,
    const int* __restrict__ sorted, void* __restrict__ out, int N)
{
    __shared__ alignas(16) unsigned short A_lds[GTILE * APITCH];     // 18560 B
    __shared__ alignas(16) unsigned char stage_lds[GTILE * 2048];    // 16384 B
    __shared__ alignas(16) float comp_lds[48 * NBASES];              // 1536 B
    __shared__ int cnt_lds[GTILE * 48];                              // 1536 B
    const int tid  = threadIdx.x;
    const int lane = tid & 63;
    const int wave = tid >> 6;
    const int isf32 = meta[0];

    for (int t = tid; t < 48 * NBASES; t += 512)
        comp_lds[t] = loadF(comp, t, isf32);
    __syncthreads();

    const int nodeBase = blockIdx.x * GTILE;
    const int dl = lane & 31;    // dim lane: dims dl*4..dl*4+3
    const int eg = lane >> 5;    // basis-half: owns bases 4*eg..4*eg+3

    {   // ---- Phase A: this wave's node ----
        const int n = nodeBase + wave;
        float acc[4][4];         // own 4 bases x 4 dims — complete sums
        #pragma unroll
        for (int b = 0; b < 4; ++b)
            #pragma unroll
            for (int i = 0; i < 4; ++i) acc[b][i] = 0.f;

        int* cnt_row = &cnt_lds[wave * 48];

        if (n < N) {
            const int start = offsets[n] + bpre[n >> 10];
            const int idx1  = n + 1;
            const int end   = offsets[idx1] + ((idx1 < N) ? bpre[idx1 >> 10] : 0);

            // pass 1: per-relation counts via wave-local LDS histogram (proven)
            if (lane < 48) cnt_row[lane] = 0;
            for (int c = start + lane; c < end; c += 64)
                atomicAdd(&cnt_row[(sorted[c] >> 16) & 63], 1);
            if (lane < 48) {
                float nv = __builtin_amdgcn_rcpf(fmaxf((float)cnt_row[lane], 1.0f));
                cnt_row[lane] = __float_as_int(nv);
            }

            if (!isf32 && start < end) {
                const unsigned short* xh = (const unsigned short*)x;
                unsigned char* buf0 = &stage_lds[wave * 2048];
                unsigned char* buf1 = (unsigned char*)&A_lds[wave * APITCH];

                for (int w0 = start; w0 < end; w0 += 64) {
                    int sv = (w0 + lane < end) ? sorted[w0 + lane] : 0;
                    const int wdeg = min(64, end - w0);
                    const int nch = (wdeg + 7) >> 3;

                    // issue chunk 0 (always 8 loads; pads read row 0, weight 0)
                    #pragma unroll
                    for (int u = 0; u < 8; ++u) {
                        unsigned qs = (unsigned)__shfl(sv, u);
                        unsigned src = (u < wdeg) ? (qs & 0xFFFFu) : 0u;
                        const unsigned short* gp = xh + (size_t)src * NDIM + lane * 2;
                        __builtin_amdgcn_global_load_lds(
                            (const __attribute__((address_space(1))) unsigned*)gp,
                            (__attribute__((address_space(3))) unsigned*)(buf0 + u * 256),
                            4, 0, 0);
                    }
                    for (int i = 0; i < nch; ++i) {
                        unsigned char* cur = (i & 1) ? buf1 : buf0;
                        if (i + 1 < nch) {
                            unsigned char* nxt = (i & 1) ? buf0 : buf1;
                            const int cb = (i + 1) * 8;
                            #pragma unroll
                            for (int u = 0; u < 8; ++u) {
                                int j = cb + u;
                                unsigned qs = (unsigned)__shfl(sv, j & 63);
                                unsigned src = (j < wdeg) ? (qs & 0xFFFFu) : 0u;
                                const unsigned short* gp = xh + (size_t)src * NDIM + lane * 2;
                                __builtin_amdgcn_global_load_lds(
                                    (const __attribute__((address_space(1))) unsigned*)gp,
                                    (__attribute__((address_space(3))) unsigned*)(nxt + u * 256),
                                    4, 0, 0);
                            }
                            asm volatile("s_waitcnt vmcnt(8)" ::: "memory");
                        } else {
                            asm volatile("s_waitcnt vmcnt(0)" ::: "memory");
                        }
                        // consume 8 edges from cur (R13 arithmetic, data from LDS)
                        const int cb0 = i * 8;
                        #pragma unroll
                        for (int u = 0; u < 8; ++u) {
                            int j = cb0 + u;
                            bool act = j < wdeg;
                            unsigned qq = (unsigned)__shfl(sv, j & 63);
                            int rel = (int)((qq >> 16) & 63u);
                            float norm = act ? __int_as_float(cnt_row[rel]) : 0.f;
                            f32x4 cw = *(const f32x4*)&comp_lds[rel * NBASES + 4 * eg];
                            uint2 xd = *(const uint2*)(cur + u * 256 + dl * 8);
                            float xs[4];
                            xs[0] = __uint_as_float(xd.x << 16)         * norm;
                            xs[1] = __uint_as_float(xd.x & 0xFFFF0000u) * norm;
                            xs[2] = __uint_as_float(xd.y << 16)         * norm;
                            xs[3] = __uint_as_float(xd.y & 0xFFFF0000u) * norm;
                            #pragma unroll
                            for (int b = 0; b < 4; ++b)
                                #pragma unroll
                                for (int i2 = 0; i2 < 4; ++i2)
                                    acc[b][i2] += cw[b] * xs[i2];
                        }
                    }
                }
            } else if (isf32) {
                // f32 fallback: R13-proven synchronous pair loop
                const float* xfp = (const float*)x;
                for (int c = start; c < end; c += 2) {
                    bool act_o = (c + eg) < end;
                    bool act_p = (c + (1 ^ eg)) < end;
                    int io = c + eg;
                    unsigned q0 = (io < end) ? (unsigned)sorted[io] : 0u;
                    unsigned qp = (unsigned)__shfl_xor((int)q0, 32);
                    int rel_o = (int)((q0 >> 16) & 63u);
                    int rel_p = (int)((qp >> 16) & 63u);
                    float nrm_o = act_o ? __int_as_float(cnt_row[rel_o]) : 0.f;
                    float nrm_p = act_p ? __int_as_float(cnt_row[rel_p]) : 0.f;
                    f32x4 cw_o = *(const f32x4*)&comp_lds[rel_o * NBASES + 4 * eg];
                    f32x4 cw_p = *(const f32x4*)&comp_lds[rel_p * NBASES + 4 * eg];
                    f32x4 xv = *(const f32x4*)(xfp + (size_t)(q0 & 0xFFFFu) * NDIM + dl * 4);
                    float xo[4], xq[4];
                    #pragma unroll
                    for (int i = 0; i < 4; ++i) {
                        xo[i] = xv[i] * nrm_o;
                        xq[i] = __shfl_xor(xv[i], 32) * nrm_p;
                    }
                    #pragma unroll
                    for (int b = 0; b < 4; ++b)
                        #pragma unroll
                        for (int i = 0; i < 4; ++i)
                            acc[b][i] += cw_o[b] * xo[i] + cw_p[b] * xq[i];
                }
            }
        }

        // epilogue: each lane's acc is complete — write own 4 bases directly.
        // (A_lds row was the 2nd stage buffer; all loads drained by vmcnt(0).)
        unsigned short* row = &A_lds[wave * APITCH];
        #pragma unroll
        for (int b = 0; b < 4; ++b) {
            uint2 p;
            p.x = pack2bf(acc[b][0], acc[b][1]);
            p.y = pack2bf(acc[b][2], acc[b][3]);
            *(uint2*)(row + (4 * eg + b) * NDIM + dl * 4) = p;
        }
        if (eg == 0) {   // root slot: node's own embedding
            uint2 xr = {0, 0};
            if (n < N) {
                if (!isf32) {
                    xr = *(const uint2*)((const unsigned short*)x + (size_t)n * NDIM + dl * 4);
                } else {
                    const float* xf = (const float*)x + (size_t)n * NDIM + dl * 4;
                    xr.x = pack2bf(xf[0], xf[1]);
                    xr.y = pack2bf(xf[2], xf[3]);
                }
            }
            *(uint2*)(row + NBASES * NDIM + dl * 4) = xr;
        }
    }
    __syncthreads();

    // ---- Phase B: [8,1152] @ [1152,128], ALL 8 waves, 16 cols each ----
    {
        const int m = lane & 15;
        const int q = lane >> 4;
        f32x4 C0 = {0, 0, 0, 0};
        const unsigned short* arow = &A_lds[(m & 7) * APITCH];   // rows 8-15 dup 0-7
        const int jb = wave * 16;
        for (int ks = 0; ks < KDIM / 32; ++ks) {
            int k = ks * 32 + q * 8;
            bfrag a = *(const bfrag*)(arow + k);
            bfrag b = *(const bfrag*)(BT + (size_t)(jb + m) * KDIM + k);
            C0 = __builtin_amdgcn_mfma_f32_16x16x32_bf16(a, b, C0, 0, 0, 0);
        }
        // C/D layout (m89/m91): col = lane&15, row = (lane>>4)*4 + reg.
        // rows 8-15 are duplicates of 0-7 — store rows < 8 only.
        int j = jb + m;
        float bj = loadF(bias, j, isf32);
        #pragma unroll
        for (int r = 0; r < 4; ++r) {
            int row16 = q * 4 + r;
            if (row16 < GTILE) {
                int n = nodeBase + row16;
                if (n < N) {
                    float v = C0[r] + bj;
                    if (isf32) ((float*)out)[(size_t)n * NDIM + j] = v;
                    else       ((unsigned short*)out)[(size_t)n * NDIM + j] = f2bf(v);
                }
            }
        }
    }
}

extern "C" void kernel_launch(void* const* d_in, const int* in_sizes, int n_in,
                              void* d_out, int out_size, void* d_ws, size_t ws_size,
                              hipStream_t stream) {
    const int* ei = (const int*)d_in[0];
    const int* et = (const int*)d_in[1];

    const int E = in_sizes[1];
    const int N = in_sizes[2] / NDIM;
    const int S = in_sizes[7] / NDIM;
    const int NB = (N + 1023) / 1024;

    // workspace layout — ~3.30 MB
    char* ws = (char*)d_ws;
    size_t off = 0;
    int* meta    = (int*)(ws + off); off += 16;
    int* hist    = (int*)(ws + off); off += (size_t)N * 4;
    int* cursor  = (int*)(ws + off); off += (size_t)N * 4;
    int* offsets = (int*)(ws + off); off = (off + (size_t)(N + 1) * 4 + 15) & ~(size_t)15;
    int* bsum    = (int*)(ws + off); off += 64 * 4;
    int* bpre    = (int*)(ws + off); off += 64 * 4;
    unsigned short* BT = (unsigned short*)(ws + off); off += (size_t)NDIM * KDIM * 2;
    int* sorted  = (int*)(ws + off); off += (size_t)E * 4;

    hipMemsetAsync(hist, 0, (size_t)2 * N * 4, stream);   // hist + cursor

    detect_k<<<1, 64, 0, stream>>>((const unsigned short*)d_in[2], ei, meta);
    {
        int T = NDIM * KDIM + S * NDIM + E;
        misc_k<<<(T + 255) / 256, 256, 0, stream>>>(
            d_in[3], d_in[5], d_in[7], meta, BT, d_out, S * NDIM, N * NDIM,
            ei, E, N, hist);
    }
    scanA_k<<<NB, 1024, 0, stream>>>(hist, N, offsets, bsum);
    scanB_k<<<1, 64, 0, stream>>>(bsum, NB, N, bpre, offsets);
    scatter_k<<<(E + 255) / 256, 256, 0, stream>>>(ei, et, E, N, meta, offsets, bpre, cursor, sorted);
    rgcn_main_k<<<(N + GTILE - 1) / GTILE, 512, 0, stream>>>(d_in[2], d_in[4], d_in[6], BT,
                                                             meta, offsets, bpre, sorted, d_out, N);
}

// Round 9
// 417.388 us; speedup vs baseline: 1.2713x; 1.2713x over previous
//
#include <hip/hip_runtime.h>

#define NDIM 128
#define NBASES 8
#define KDIM 1152            // 8*128 (bases) + 128 (root slot)
#define GTILE 8              // nodes per block = waves per block (512 threads)
#define APITCH 1160          // shorts; row stride 2320 B (16B-divisible)

typedef __attribute__((ext_vector_type(8))) __bf16 bfrag;
typedef __attribute__((ext_vector_type(4))) float f32x4;

__device__ __forceinline__ float bf2f(unsigned short b) {
    return __uint_as_float(((unsigned)b) << 16);
}
__device__ __forceinline__ unsigned short f2bf(float f) {
    unsigned u = __float_as_uint(f);
    unsigned r = u + 0x7FFFu + ((u >> 16) & 1u);   // RNE
    return (unsigned short)(r >> 16);
}
__device__ __forceinline__ unsigned pack2bf(float lo, float hi) {
    return (unsigned)f2bf(lo) | ((unsigned)f2bf(hi) << 16);
}
__device__ __forceinline__ float loadF(const void* p, int idx, int isf32) {
    return isf32 ? ((const float*)p)[idx] : bf2f(((const unsigned short*)p)[idx]);
}

// ---------- dtype sniffing (R7-proven ILP version) ----------
__global__ void detect_k(const unsigned short* __restrict__ xs,
                         const int* __restrict__ ei, int* __restrict__ meta) {
    if (threadIdx.x != 0 || blockIdx.x != 0) return;
    const uint4* xv = (const uint4*)xs;
    unsigned f32m = 0;
    uint4 bx[16];
    #pragma unroll
    for (int i = 0; i < 16; ++i) bx[i] = xv[i];
    #pragma unroll
    for (int i = 0; i < 16; ++i) {
        unsigned a = bx[i].x, b = bx[i].y, c = bx[i].z, d = bx[i].w;
        f32m |= (((a & 0xFFFFu) >> 7) & 0xFFu) > 124u;
        f32m |= (((b & 0xFFFFu) >> 7) & 0xFFu) > 124u;
        f32m |= (((c & 0xFFFFu) >> 7) & 0xFFu) > 124u;
        f32m |= (((d & 0xFFFFu) >> 7) & 0xFFu) > 124u;
    }
    const uint4* ev = (const uint4*)ei;
    unsigned nzm = 0;
    for (int r = 0; r < 4; ++r) {
        uint4 be[16];
        #pragma unroll
        for (int i = 0; i < 16; ++i) be[i] = ev[r * 16 + i];
        #pragma unroll
        for (int i = 0; i < 16; ++i) nzm |= be[i].y | be[i].w;
    }
    meta[0] = f32m ? 1 : 0;
    meta[1] = nzm ? 0 : 1;
}

// merged: BT build + special-embedding copy + dst-histogram (R9-proven)
__global__ void misc_k(const void* __restrict__ basis, const void* __restrict__ root,
                       const void* __restrict__ se, const int* __restrict__ meta,
                       unsigned short* __restrict__ BT, void* __restrict__ out,
                       int scount, int sbase,
                       const int* __restrict__ ei, int E, int N, int* __restrict__ hist) {
    int t = blockIdx.x * 256 + threadIdx.x;
    int isf32 = meta[0];
    if (t < NDIM * KDIM) {
        int j = t / KDIM, k = t % KDIM;
        float v = (k < NBASES * NDIM) ? loadF(basis, k * NDIM + j, isf32)
                                      : loadF(root, (k - NBASES * NDIM) * NDIM + j, isf32);
        BT[t] = f2bf(v);
    } else {
        int u = t - NDIM * KDIM;
        if (u < scount) {
            float v = loadF(se, u, isf32);
            if (isf32) ((float*)out)[sbase + u] = v;
            else       ((unsigned short*)out)[sbase + u] = f2bf(v);
        } else {
            int e = u - scount;
            if (e < E) {
                int dst = meta[1] ? ei[2 * (E + e)] : ei[E + e];
                dst = min(max(dst, 0), N - 1);
                atomicAdd(&hist[dst], 1);
            }
        }
    }
}

// ---------- hierarchical exclusive scan (R9-proven: consumers add bpre) ----------
__global__ void scanA_k(const int* __restrict__ hist, int N,
                        int* __restrict__ offsets, int* __restrict__ bsum) {
    __shared__ int s[1024];
    int tid = threadIdx.x;
    int idx = blockIdx.x * 1024 + tid;
    int v = (idx < N) ? hist[idx] : 0;
    s[tid] = v;
    __syncthreads();
    for (int off = 1; off < 1024; off <<= 1) {
        int t = 0;
        if (tid >= off) t = s[tid - off];
        __syncthreads();
        if (tid >= off) s[tid] += t;
        __syncthreads();
    }
    if (idx < N) offsets[idx] = s[tid] - v;           // exclusive within block
    if (tid == 1023) bsum[blockIdx.x] = s[1023];
}
__global__ void scanB_k(const int* __restrict__ bsum, int NB, int N,
                        int* __restrict__ bpre, int* __restrict__ offsets) {
    __shared__ int s[64];
    int tid = threadIdx.x;
    int v = (tid < NB) ? bsum[tid] : 0;
    s[tid] = v;
    __syncthreads();
    for (int off = 1; off < 64; off <<= 1) {
        int t = 0;
        if (tid >= off) t = s[tid - off];
        __syncthreads();
        if (tid >= off) s[tid] += t;
        __syncthreads();
    }
    if (tid < NB) bpre[tid] = s[tid] - v;
    if (tid == NB - 1) offsets[N] = s[tid];           // grand total (absolute)
}

__global__ void scatter_k(const int* __restrict__ ei, const int* __restrict__ et,
                          int E, int N, const int* __restrict__ meta,
                          const int* __restrict__ offsets, const int* __restrict__ bpre,
                          int* __restrict__ cursor, int* __restrict__ sorted) {
    int e = blockIdx.x * 256 + threadIdx.x;
    if (e >= E) return;
    int i64 = meta[1];
    int src = i64 ? ei[2 * e] : ei[e];
    int dst = i64 ? ei[2 * (E + e)] : ei[E + e];
    int rel = i64 ? et[2 * e] : et[e];
    src = min(max(src, 0), N - 1);
    dst = min(max(dst, 0), N - 1);
    rel = rel & 63;
    int pos = offsets[dst] + bpre[dst >> 10] + atomicAdd(&cursor[dst], 1);
    sorted[pos] = src | (rel << 16);
}

// ---------- main fused kernel ----------
// R16 = R13's PROVEN Phase A (179us, spill-free) with ONE structural change:
// GTILE 16 -> 8 (512-thread blocks, __launch_bounds__(512,8)). Rationale:
// R15's (otherwise-failed) run measured occupancy 56 -> 84% at GTILE=8 —
// barrier imbalance (block waits on max degree among its nodes) halves, and
// 4 blocks/CU (vs 2) gives unsynchronized work to fill barrier stalls.
// LDS 21.6KB/block -> 4 blocks x 8 waves = 32 waves/CU ceiling.
// Phase B = R15's all-8-waves variant (correctness-proven): 16 cols/wave,
// A rows 8-15 duplicated via m&7, rows >= 8 discarded at store.
// NO async staging, NO inline asm (R15 falsified that mechanism: 2.2x slower,
// WRITE_SIZE 295MB scratch explosion).
__global__ __launch_bounds__(512, 8) void rgcn_main_k(
    const void* __restrict__ x, const void* __restrict__ comp,
    const void* __restrict__ bias, const unsigned short* __restrict__ BT,
    const int* __restrict__ meta, const int* __restrict__ offsets,
    const int* __restrict__ bpre,
    const int* __restrict__ sorted, void* __restrict__ out, int N)
{
    __shared__ alignas(16) unsigned short A_lds[GTILE * APITCH];   // 18560 B
    __shared__ alignas(16) float comp_lds[48 * NBASES];            // 1536 B
    __shared__ int cnt_lds[GTILE * 48];                            // 1536 B
    const int tid  = threadIdx.x;
    const int lane = tid & 63;
    const int wave = tid >> 6;
    const int isf32 = meta[0];

    for (int t = tid; t < 48 * NBASES; t += 512)
        comp_lds[t] = loadF(comp, t, isf32);
    __syncthreads();

    const int nodeBase = blockIdx.x * GTILE;
    const int dl = lane & 31;    // dim lane: dims dl*4..dl*4+3
    const int eg = lane >> 5;    // edge-group half: owns bases 4*eg..4*eg+3

    {   // ---- Phase A: this wave's node (R13 verbatim) ----
        const int n = nodeBase + wave;
        float acc[4][4];         // own 4 bases x 4 dims — complete sums
        #pragma unroll
        for (int b = 0; b < 4; ++b)
            #pragma unroll
            for (int i = 0; i < 4; ++i) acc[b][i] = 0.f;

        int* cnt_row = &cnt_lds[wave * 48];

        if (n < N) {
            const int start = offsets[n] + bpre[n >> 10];
            const int idx1  = n + 1;
            const int end   = offsets[idx1] + ((idx1 < N) ? bpre[idx1 >> 10] : 0);

            // pass 1: per-relation counts via wave-local LDS histogram (proven)
            if (lane < 48) cnt_row[lane] = 0;
            for (int c = start + lane; c < end; c += 64)
                atomicAdd(&cnt_row[(sorted[c] >> 16) & 63], 1);
            if (lane < 48) {
                float nv = __builtin_amdgcn_rcpf(fmaxf((float)cnt_row[lane], 1.0f));
                cnt_row[lane] = __float_as_int(nv);
            }

            // pass 2: gather + accumulate; own edge loaded, partner via shfl_xor
            if (!isf32) {
                const unsigned short* xh = (const unsigned short*)x;
                if (start < end) {
                    int i0 = start + eg;
                    unsigned q0 = (i0 < end) ? (unsigned)sorted[i0] : 0u;
                    int i1 = start + 2 + eg;
                    unsigned q1 = (i1 < end) ? (unsigned)sorted[i1] : 0u;
                    uint2 xa0 = *(const uint2*)(xh + (size_t)(q0 & 0xFFFFu) * NDIM + dl * 4);
                    uint2 xa1 = *(const uint2*)(xh + (size_t)(q1 & 0xFFFFu) * NDIM + dl * 4);
                    int i2 = start + 4 + eg;
                    unsigned q2 = (i2 < end) ? (unsigned)sorted[i2] : 0u;
                    for (int c = start; c < end; c += 2) {
                        // issue next x-row load (2 ahead) + prefetch next sorted entry
                        uint2 xa2 = *(const uint2*)(xh + (size_t)(q2 & 0xFFFFu) * NDIM + dl * 4);
                        int i3 = c + 6 + eg;
                        unsigned q3 = (i3 < end) ? (unsigned)sorted[i3] : 0u;

                        // current pair: own edge (c+eg) in regs; partner via shfl
                        bool act_o = (c + eg) < end;
                        bool act_p = (c + (1 ^ eg)) < end;
                        unsigned qp = (unsigned)__shfl_xor((int)q0, 32);
                        int rel_o = (int)((q0 >> 16) & 63u);
                        int rel_p = (int)((qp >> 16) & 63u);
                        float nrm_o = act_o ? __int_as_float(cnt_row[rel_o]) : 0.f;
                        float nrm_p = act_p ? __int_as_float(cnt_row[rel_p]) : 0.f;
                        f32x4 cw_o = *(const f32x4*)&comp_lds[rel_o * NBASES + 4 * eg];
                        f32x4 cw_p = *(const f32x4*)&comp_lds[rel_p * NBASES + 4 * eg];
                        unsigned px = (unsigned)__shfl_xor((int)xa0.x, 32);
                        unsigned py = (unsigned)__shfl_xor((int)xa0.y, 32);
                        float xo[4], xq[4];
                        xo[0] = __uint_as_float(xa0.x << 16)          * nrm_o;
                        xo[1] = __uint_as_float(xa0.x & 0xFFFF0000u)  * nrm_o;
                        xo[2] = __uint_as_float(xa0.y << 16)          * nrm_o;
                        xo[3] = __uint_as_float(xa0.y & 0xFFFF0000u)  * nrm_o;
                        xq[0] = __uint_as_float(px << 16)             * nrm_p;
                        xq[1] = __uint_as_float(px & 0xFFFF0000u)     * nrm_p;
                        xq[2] = __uint_as_float(py << 16)             * nrm_p;
                        xq[3] = __uint_as_float(py & 0xFFFF0000u)     * nrm_p;
                        #pragma unroll
                        for (int b = 0; b < 4; ++b)
                            #pragma unroll
                            for (int i = 0; i < 4; ++i)
                                acc[b][i] += cw_o[b] * xo[i] + cw_p[b] * xq[i];
                        q0 = q1; q1 = q2; q2 = q3;
                        xa0 = xa1; xa1 = xa2;
                    }
                }
            } else {
                const float* xfp = (const float*)x;
                for (int c = start; c < end; c += 2) {
                    bool act_o = (c + eg) < end;
                    bool act_p = (c + (1 ^ eg)) < end;
                    int io = c + eg;
                    unsigned q0 = (io < end) ? (unsigned)sorted[io] : 0u;
                    unsigned qp = (unsigned)__shfl_xor((int)q0, 32);
                    int rel_o = (int)((q0 >> 16) & 63u);
                    int rel_p = (int)((qp >> 16) & 63u);
                    float nrm_o = act_o ? __int_as_float(cnt_row[rel_o]) : 0.f;
                    float nrm_p = act_p ? __int_as_float(cnt_row[rel_p]) : 0.f;
                    f32x4 cw_o = *(const f32x4*)&comp_lds[rel_o * NBASES + 4 * eg];
                    f32x4 cw_p = *(const f32x4*)&comp_lds[rel_p * NBASES + 4 * eg];
                    f32x4 xv = *(const f32x4*)(xfp + (size_t)(q0 & 0xFFFFu) * NDIM + dl * 4);
                    float xo[4], xq[4];
                    #pragma unroll
                    for (int i = 0; i < 4; ++i) {
                        xo[i] = xv[i] * nrm_o;
                        xq[i] = __shfl_xor(xv[i], 32) * nrm_p;
                    }
                    #pragma unroll
                    for (int b = 0; b < 4; ++b)
                        #pragma unroll
                        for (int i = 0; i < 4; ++i)
                            acc[b][i] += cw_o[b] * xo[i] + cw_p[b] * xq[i];
                }
            }
        }

        // epilogue: each lane's acc is complete — write own 4 bases directly
        unsigned short* row = &A_lds[wave * APITCH];
        #pragma unroll
        for (int b = 0; b < 4; ++b) {
            uint2 p;
            p.x = pack2bf(acc[b][0], acc[b][1]);
            p.y = pack2bf(acc[b][2], acc[b][3]);
            *(uint2*)(row + (4 * eg + b) * NDIM + dl * 4) = p;
        }
        if (eg == 0) {   // root slot: node's own embedding
            uint2 xr = {0, 0};
            if (n < N) {
                if (!isf32) {
                    xr = *(const uint2*)((const unsigned short*)x + (size_t)n * NDIM + dl * 4);
                } else {
                    const float* xf = (const float*)x + (size_t)n * NDIM + dl * 4;
                    xr.x = pack2bf(xf[0], xf[1]);
                    xr.y = pack2bf(xf[2], xf[3]);
                }
            }
            *(uint2*)(row + NBASES * NDIM + dl * 4) = xr;
        }
    }
    __syncthreads();

    // ---- Phase B: [8,1152] @ [1152,128], ALL 8 waves, 16 cols each ----
    // (R15-proven correct: rows 8-15 duplicate 0-7 via m&7, discarded at store)
    {
        const int m = lane & 15;
        const int q = lane >> 4;
        f32x4 C0 = {0, 0, 0, 0};
        const unsigned short* arow = &A_lds[(m & 7) * APITCH];
        const int jb = wave * 16;
        for (int ks = 0; ks < KDIM / 32; ++ks) {
            int k = ks * 32 + q * 8;
            bfrag a = *(const bfrag*)(arow + k);
            bfrag b = *(const bfrag*)(BT + (size_t)(jb + m) * KDIM + k);
            C0 = __builtin_amdgcn_mfma_f32_16x16x32_bf16(a, b, C0, 0, 0, 0);
        }
        // C/D layout (m89/m91): col = lane&15, row = (lane>>4)*4 + reg
        int j = jb + m;
        float bj = loadF(bias, j, isf32);
        #pragma unroll
        for (int r = 0; r < 4; ++r) {
            int row16 = q * 4 + r;
            if (row16 < GTILE) {
                int n = nodeBase + row16;
                if (n < N) {
                    float v = C0[r] + bj;
                    if (isf32) ((float*)out)[(size_t)n * NDIM + j] = v;
                    else       ((unsigned short*)out)[(size_t)n * NDIM + j] = f2bf(v);
                }
            }
        }
    }
}

extern "C" void kernel_launch(void* const* d_in, const int* in_sizes, int n_in,
                              void* d_out, int out_size, void* d_ws, size_t ws_size,
                              hipStream_t stream) {
    const int* ei = (const int*)d_in[0];
    const int* et = (const int*)d_in[1];

    const int E = in_sizes[1];
    const int N = in_sizes[2] / NDIM;
    const int S = in_sizes[7] / NDIM;
    const int NB = (N + 1023) / 1024;

    // workspace layout — ~3.30 MB
    char* ws = (char*)d_ws;
    size_t off = 0;
    int* meta    = (int*)(ws + off); off += 16;
    int* hist    = (int*)(ws + off); off += (size_t)N * 4;
    int* cursor  = (int*)(ws + off); off += (size_t)N * 4;
    int* offsets = (int*)(ws + off); off = (off + (size_t)(N + 1) * 4 + 15) & ~(size_t)15;
    int* bsum    = (int*)(ws + off); off += 64 * 4;
    int* bpre    = (int*)(ws + off); off += 64 * 4;
    unsigned short* BT = (unsigned short*)(ws + off); off += (size_t)NDIM * KDIM * 2;
    int* sorted  = (int*)(ws + off); off += (size_t)E * 4;

    hipMemsetAsync(hist, 0, (size_t)2 * N * 4, stream);   // hist + cursor

    detect_k<<<1, 64, 0, stream>>>((const unsigned short*)d_in[2], ei, meta);
    {
        int T = NDIM * KDIM + S * NDIM + E;
        misc_k<<<(T + 255) / 256, 256, 0, stream>>>(
            d_in[3], d_in[5], d_in[7], meta, BT, d_out, S * NDIM, N * NDIM,
            ei, E, N, hist);
    }
    scanA_k<<<NB, 1024, 0, stream>>>(hist, N, offsets, bsum);
    scanB_k<<<1, 64, 0, stream>>>(bsum, NB, N, bpre, offsets);
    scatter_k<<<(E + 255) / 256, 256, 0, stream>>>(ei, et, E, N, meta, offsets, bpre, cursor, sorted);
    rgcn_main_k<<<(N + GTILE - 1) / GTILE, 512, 0, stream>>>(d_in[2], d_in[4], d_in[6], BT,
                                                             meta, offsets, bpre, sorted, d_out, N);
}

// Round 10
// 322.357 us; speedup vs baseline: 1.6460x; 1.2948x over previous
//
#include <hip/hip_runtime.h>

#define NDIM 128
#define NBASES 8
#define KDIM 1152            // 8*128 (bases) + 128 (root slot)
#define GTILE 16
#define APITCH 1160          // shorts; row stride 2320 B (16B-divisible)

typedef __attribute__((ext_vector_type(8))) __bf16 bfrag;
typedef __attribute__((ext_vector_type(4))) float f32x4;

__device__ __forceinline__ float bf2f(unsigned short b) {
    return __uint_as_float(((unsigned)b) << 16);
}
__device__ __forceinline__ unsigned short f2bf(float f) {
    unsigned u = __float_as_uint(f);
    unsigned r = u + 0x7FFFu + ((u >> 16) & 1u);   // RNE
    return (unsigned short)(r >> 16);
}
__device__ __forceinline__ unsigned pack2bf(float lo, float hi) {
    return (unsigned)f2bf(lo) | ((unsigned)f2bf(hi) << 16);
}
__device__ __forceinline__ float loadF(const void* p, int idx, int isf32) {
    return isf32 ? ((const float*)p)[idx] : bf2f(((const unsigned short*)p)[idx]);
}

// ---------- dtype sniffing (R7-proven ILP version) ----------
__global__ void detect_k(const unsigned short* __restrict__ xs,
                         const int* __restrict__ ei, int* __restrict__ meta) {
    if (threadIdx.x != 0 || blockIdx.x != 0) return;
    const uint4* xv = (const uint4*)xs;
    unsigned f32m = 0;
    uint4 bx[16];
    #pragma unroll
    for (int i = 0; i < 16; ++i) bx[i] = xv[i];
    #pragma unroll
    for (int i = 0; i < 16; ++i) {
        unsigned a = bx[i].x, b = bx[i].y, c = bx[i].z, d = bx[i].w;
        f32m |= (((a & 0xFFFFu) >> 7) & 0xFFu) > 124u;
        f32m |= (((b & 0xFFFFu) >> 7) & 0xFFu) > 124u;
        f32m |= (((c & 0xFFFFu) >> 7) & 0xFFu) > 124u;
        f32m |= (((d & 0xFFFFu) >> 7) & 0xFFu) > 124u;
    }
    const uint4* ev = (const uint4*)ei;
    unsigned nzm = 0;
    for (int r = 0; r < 4; ++r) {
        uint4 be[16];
        #pragma unroll
        for (int i = 0; i < 16; ++i) be[i] = ev[r * 16 + i];
        #pragma unroll
        for (int i = 0; i < 16; ++i) nzm |= be[i].y | be[i].w;
    }
    meta[0] = f32m ? 1 : 0;
    meta[1] = nzm ? 0 : 1;
}

// merged: BT build + special-embedding copy + dst-histogram (R9-proven)
__global__ void misc_k(const void* __restrict__ basis, const void* __restrict__ root,
                       const void* __restrict__ se, const int* __restrict__ meta,
                       unsigned short* __restrict__ BT, void* __restrict__ out,
                       int scount, int sbase,
                       const int* __restrict__ ei, int E, int N, int* __restrict__ hist) {
    int t = blockIdx.x * 256 + threadIdx.x;
    int isf32 = meta[0];
    if (t < NDIM * KDIM) {
        int j = t / KDIM, k = t % KDIM;
        float v = (k < NBASES * NDIM) ? loadF(basis, k * NDIM + j, isf32)
                                      : loadF(root, (k - NBASES * NDIM) * NDIM + j, isf32);
        BT[t] = f2bf(v);
    } else {
        int u = t - NDIM * KDIM;
        if (u < scount) {
            float v = loadF(se, u, isf32);
            if (isf32) ((float*)out)[sbase + u] = v;
            else       ((unsigned short*)out)[sbase + u] = f2bf(v);
        } else {
            int e = u - scount;
            if (e < E) {
                int dst = meta[1] ? ei[2 * (E + e)] : ei[E + e];
                dst = min(max(dst, 0), N - 1);
                atomicAdd(&hist[dst], 1);
            }
        }
    }
}

// ---------- hierarchical exclusive scan (R9-proven: consumers add bpre) ----------
__global__ void scanA_k(const int* __restrict__ hist, int N,
                        int* __restrict__ offsets, int* __restrict__ bsum) {
    __shared__ int s[1024];
    int tid = threadIdx.x;
    int idx = blockIdx.x * 1024 + tid;
    int v = (idx < N) ? hist[idx] : 0;
    s[tid] = v;
    __syncthreads();
    for (int off = 1; off < 1024; off <<= 1) {
        int t = 0;
        if (tid >= off) t = s[tid - off];
        __syncthreads();
        if (tid >= off) s[tid] += t;
        __syncthreads();
    }
    if (idx < N) offsets[idx] = s[tid] - v;           // exclusive within block
    if (tid == 1023) bsum[blockIdx.x] = s[1023];
}
__global__ void scanB_k(const int* __restrict__ bsum, int NB, int N,
                        int* __restrict__ bpre, int* __restrict__ offsets) {
    __shared__ int s[64];
    int tid = threadIdx.x;
    int v = (tid < NB) ? bsum[tid] : 0;
    s[tid] = v;
    __syncthreads();
    for (int off = 1; off < 64; off <<= 1) {
        int t = 0;
        if (tid >= off) t = s[tid - off];
        __syncthreads();
        if (tid >= off) s[tid] += t;
        __syncthreads();
    }
    if (tid < NB) bpre[tid] = s[tid] - v;
    if (tid == NB - 1) offsets[N] = s[tid];           // grand total (absolute)
}

__global__ void scatter_k(const int* __restrict__ ei, const int* __restrict__ et,
                          int E, int N, const int* __restrict__ meta,
                          const int* __restrict__ offsets, const int* __restrict__ bpre,
                          int* __restrict__ cursor, int* __restrict__ sorted) {
    int e = blockIdx.x * 256 + threadIdx.x;
    if (e >= E) return;
    int i64 = meta[1];
    int src = i64 ? ei[2 * e] : ei[e];
    int dst = i64 ? ei[2 * (E + e)] : ei[E + e];
    int rel = i64 ? et[2 * e] : et[e];
    src = min(max(src, 0), N - 1);
    dst = min(max(dst, 0), N - 1);
    rel = rel & 63;
    int pos = offsets[dst] + bpre[dst >> 10] + atomicAdd(&cursor[dst], 1);
    sorted[pos] = src | (rel << 16);
}

// ---------- main fused kernel ----------
// R17 = R13 (GTILE=16, 179us proven, spill-free) with ONE change: bf16 gather
// rotation deepened 2 -> 4 rows in flight (q0..q4 / xa0..xa3 + issue xa4).
// Rationale: R16 proved occupancy is NOT the binding resource (83% occ,
// 278us); per-wave MLP is. Steady-state stall per edge-pair drops ~L/2 ->
// ~L/4. Live set ~50-55 VGPR (R13's lean 16-reg acc gives headroom that
// R11's fat-acc attempt lacked). Tripwire: WRITE_SIZE > 30MB = spilled.
// GTILE=8 rejected (R16: Phase B L2 traffic + MFMA doubled, 4x LDS conflicts).
__global__ __launch_bounds__(1024, 8) void rgcn_main_k(
    const void* __restrict__ x, const void* __restrict__ comp,
    const void* __restrict__ bias, const unsigned short* __restrict__ BT,
    const int* __restrict__ meta, const int* __restrict__ offsets,
    const int* __restrict__ bpre,
    const int* __restrict__ sorted, void* __restrict__ out, int N)
{
    __shared__ alignas(16) unsigned short A_lds[GTILE * APITCH];   // 37120 B
    __shared__ alignas(16) float comp_lds[48 * NBASES];            // 1536 B
    __shared__ int cnt_lds[GTILE * 48];                            // 3072 B
    const int tid  = threadIdx.x;
    const int lane = tid & 63;
    const int wave = tid >> 6;
    const int isf32 = meta[0];

    for (int t = tid; t < 48 * NBASES; t += 1024)
        comp_lds[t] = loadF(comp, t, isf32);
    __syncthreads();

    const int nodeBase = blockIdx.x * GTILE;
    const int dl = lane & 31;    // dim lane: dims dl*4..dl*4+3
    const int eg = lane >> 5;    // edge-group half: owns bases 4*eg..4*eg+3

    {   // ---- Phase A: this wave's node ----
        const int n = nodeBase + wave;
        float acc[4][4];         // own 4 bases x 4 dims — complete sums
        #pragma unroll
        for (int b = 0; b < 4; ++b)
            #pragma unroll
            for (int i = 0; i < 4; ++i) acc[b][i] = 0.f;

        int* cnt_row = &cnt_lds[wave * 48];

        if (n < N) {
            const int start = offsets[n] + bpre[n >> 10];
            const int idx1  = n + 1;
            const int end   = offsets[idx1] + ((idx1 < N) ? bpre[idx1 >> 10] : 0);

            // pass 1: per-relation counts via wave-local LDS histogram (proven)
            if (lane < 48) cnt_row[lane] = 0;
            for (int c = start + lane; c < end; c += 64)
                atomicAdd(&cnt_row[(sorted[c] >> 16) & 63], 1);
            if (lane < 48) {
                float nv = __builtin_amdgcn_rcpf(fmaxf((float)cnt_row[lane], 1.0f));
                cnt_row[lane] = __float_as_int(nv);
            }

            // pass 2: gather + accumulate; own edge loaded, partner via shfl_xor.
            // Rotation depth 4 (R17 change): xa0..xa3 buffered, xa4 issuing.
            if (!isf32) {
                const unsigned short* xh = (const unsigned short*)x;
                if (start < end) {
                    unsigned q0 = (start + eg     < end) ? (unsigned)sorted[start + eg]     : 0u;
                    unsigned q1 = (start + 2 + eg < end) ? (unsigned)sorted[start + 2 + eg] : 0u;
                    unsigned q2 = (start + 4 + eg < end) ? (unsigned)sorted[start + 4 + eg] : 0u;
                    unsigned q3 = (start + 6 + eg < end) ? (unsigned)sorted[start + 6 + eg] : 0u;
                    uint2 xa0 = *(const uint2*)(xh + (size_t)(q0 & 0xFFFFu) * NDIM + dl * 4);
                    uint2 xa1 = *(const uint2*)(xh + (size_t)(q1 & 0xFFFFu) * NDIM + dl * 4);
                    uint2 xa2 = *(const uint2*)(xh + (size_t)(q2 & 0xFFFFu) * NDIM + dl * 4);
                    uint2 xa3 = *(const uint2*)(xh + (size_t)(q3 & 0xFFFFu) * NDIM + dl * 4);
                    unsigned q4 = (start + 8 + eg < end) ? (unsigned)sorted[start + 8 + eg] : 0u;
                    for (int c = start; c < end; c += 2) {
                        // issue next x-row load (4 ahead) + prefetch next sorted entry
                        uint2 xa4 = *(const uint2*)(xh + (size_t)(q4 & 0xFFFFu) * NDIM + dl * 4);
                        unsigned q5 = (c + 10 + eg < end) ? (unsigned)sorted[c + 10 + eg] : 0u;

                        // current pair: own edge (c+eg) in regs; partner via shfl
                        bool act_o = (c + eg) < end;
                        bool act_p = (c + (1 ^ eg)) < end;
                        unsigned qp = (unsigned)__shfl_xor((int)q0, 32);
                        int rel_o = (int)((q0 >> 16) & 63u);
                        int rel_p = (int)((qp >> 16) & 63u);
                        float nrm_o = act_o ? __int_as_float(cnt_row[rel_o]) : 0.f;
                        float nrm_p = act_p ? __int_as_float(cnt_row[rel_p]) : 0.f;
                        f32x4 cw_o = *(const f32x4*)&comp_lds[rel_o * NBASES + 4 * eg];
                        f32x4 cw_p = *(const f32x4*)&comp_lds[rel_p * NBASES + 4 * eg];
                        unsigned px = (unsigned)__shfl_xor((int)xa0.x, 32);
                        unsigned py = (unsigned)__shfl_xor((int)xa0.y, 32);
                        float xo[4], xq[4];
                        xo[0] = __uint_as_float(xa0.x << 16)          * nrm_o;
                        xo[1] = __uint_as_float(xa0.x & 0xFFFF0000u)  * nrm_o;
                        xo[2] = __uint_as_float(xa0.y << 16)          * nrm_o;
                        xo[3] = __uint_as_float(xa0.y & 0xFFFF0000u)  * nrm_o;
                        xq[0] = __uint_as_float(px << 16)             * nrm_p;
                        xq[1] = __uint_as_float(px & 0xFFFF0000u)     * nrm_p;
                        xq[2] = __uint_as_float(py << 16)             * nrm_p;
                        xq[3] = __uint_as_float(py & 0xFFFF0000u)     * nrm_p;
                        #pragma unroll
                        for (int b = 0; b < 4; ++b)
                            #pragma unroll
                            for (int i = 0; i < 4; ++i)
                                acc[b][i] += cw_o[b] * xo[i] + cw_p[b] * xq[i];
                        q0 = q1; q1 = q2; q2 = q3; q3 = q4; q4 = q5;
                        xa0 = xa1; xa1 = xa2; xa2 = xa3; xa3 = xa4;
                    }
                }
            } else {
                // f32 fallback: R13-proven synchronous pair loop
                const float* xfp = (const float*)x;
                for (int c = start; c < end; c += 2) {
                    bool act_o = (c + eg) < end;
                    bool act_p = (c + (1 ^ eg)) < end;
                    int io = c + eg;
                    unsigned q0 = (io < end) ? (unsigned)sorted[io] : 0u;
                    unsigned qp = (unsigned)__shfl_xor((int)q0, 32);
                    int rel_o = (int)((q0 >> 16) & 63u);
                    int rel_p = (int)((qp >> 16) & 63u);
                    float nrm_o = act_o ? __int_as_float(cnt_row[rel_o]) : 0.f;
                    float nrm_p = act_p ? __int_as_float(cnt_row[rel_p]) : 0.f;
                    f32x4 cw_o = *(const f32x4*)&comp_lds[rel_o * NBASES + 4 * eg];
                    f32x4 cw_p = *(const f32x4*)&comp_lds[rel_p * NBASES + 4 * eg];
                    f32x4 xv = *(const f32x4*)(xfp + (size_t)(q0 & 0xFFFFu) * NDIM + dl * 4);
                    float xo[4], xq[4];
                    #pragma unroll
                    for (int i = 0; i < 4; ++i) {
                        xo[i] = xv[i] * nrm_o;
                        xq[i] = __shfl_xor(xv[i], 32) * nrm_p;
                    }
                    #pragma unroll
                    for (int b = 0; b < 4; ++b)
                        #pragma unroll
                        for (int i = 0; i < 4; ++i)
                            acc[b][i] += cw_o[b] * xo[i] + cw_p[b] * xq[i];
                }
            }
        }

        // epilogue: each lane's acc is complete — write own 4 bases directly
        unsigned short* row = &A_lds[wave * APITCH];
        #pragma unroll
        for (int b = 0; b < 4; ++b) {
            uint2 p;
            p.x = pack2bf(acc[b][0], acc[b][1]);
            p.y = pack2bf(acc[b][2], acc[b][3]);
            *(uint2*)(row + (4 * eg + b) * NDIM + dl * 4) = p;
        }
        if (eg == 0) {   // root slot: node's own embedding
            uint2 xr = {0, 0};
            if (n < N) {
                if (!isf32) {
                    xr = *(const uint2*)((const unsigned short*)x + (size_t)n * NDIM + dl * 4);
                } else {
                    const float* xf = (const float*)x + (size_t)n * NDIM + dl * 4;
                    xr.x = pack2bf(xf[0], xf[1]);
                    xr.y = pack2bf(xf[2], xf[3]);
                }
            }
            *(uint2*)(row + NBASES * NDIM + dl * 4) = xr;
        }
    }
    __syncthreads();

    // ---- Phase B: [16,1152] @ [1152,128], waves 0..3, 32 cols each ----
    if (wave < 4) {
        const int m = lane & 15;
        const int q = lane >> 4;
        f32x4 C0 = {0,0,0,0}, C1 = {0,0,0,0};
        const unsigned short* arow = &A_lds[m * APITCH];
        const int jb = wave * 32;
        for (int ks = 0; ks < KDIM / 32; ++ks) {
            int k = ks * 32 + q * 8;
            bfrag a  = *(const bfrag*)(arow + k);
            bfrag b0 = *(const bfrag*)(BT + (size_t)(jb +  0 + m) * KDIM + k);
            bfrag b1 = *(const bfrag*)(BT + (size_t)(jb + 16 + m) * KDIM + k);
            C0 = __builtin_amdgcn_mfma_f32_16x16x32_bf16(a, b0, C0, 0, 0, 0);
            C1 = __builtin_amdgcn_mfma_f32_16x16x32_bf16(a, b1, C1, 0, 0, 0);
        }
        // C/D layout (m89/m91): col = lane&15, row = (lane>>4)*4 + reg
        #pragma unroll
        for (int t = 0; t < 2; ++t) {
            f32x4 Ct = t ? C1 : C0;
            int j = jb + t * 16 + m;
            float bj = loadF(bias, j, isf32);
            #pragma unroll
            for (int r = 0; r < 4; ++r) {
                int n = nodeBase + q * 4 + r;
                if (n < N) {
                    float v = Ct[r] + bj;
                    if (isf32) ((float*)out)[(size_t)n * NDIM + j] = v;
                    else       ((unsigned short*)out)[(size_t)n * NDIM + j] = f2bf(v);
                }
            }
        }
    }
}

extern "C" void kernel_launch(void* const* d_in, const int* in_sizes, int n_in,
                              void* d_out, int out_size, void* d_ws, size_t ws_size,
                              hipStream_t stream) {
    const int* ei = (const int*)d_in[0];
    const int* et = (const int*)d_in[1];

    const int E = in_sizes[1];
    const int N = in_sizes[2] / NDIM;
    const int S = in_sizes[7] / NDIM;
    const int NB = (N + 1023) / 1024;

    // workspace layout — ~3.30 MB
    char* ws = (char*)d_ws;
    size_t off = 0;
    int* meta    = (int*)(ws + off); off += 16;
    int* hist    = (int*)(ws + off); off += (size_t)N * 4;
    int* cursor  = (int*)(ws + off); off += (size_t)N * 4;
    int* offsets = (int*)(ws + off); off = (off + (size_t)(N + 1) * 4 + 15) & ~(size_t)15;
    int* bsum    = (int*)(ws + off); off += 64 * 4;
    int* bpre    = (int*)(ws + off); off += 64 * 4;
    unsigned short* BT = (unsigned short*)(ws + off); off += (size_t)NDIM * KDIM * 2;
    int* sorted  = (int*)(ws + off); off += (size_t)E * 4;

    hipMemsetAsync(hist, 0, (size_t)2 * N * 4, stream);   // hist + cursor

    detect_k<<<1, 64, 0, stream>>>((const unsigned short*)d_in[2], ei, meta);
    {
        int T = NDIM * KDIM + S * NDIM + E;
        misc_k<<<(T + 255) / 256, 256, 0, stream>>>(
            d_in[3], d_in[5], d_in[7], meta, BT, d_out, S * NDIM, N * NDIM,
            ei, E, N, hist);
    }
    scanA_k<<<NB, 1024, 0, stream>>>(hist, N, offsets, bsum);
    scanB_k<<<1, 64, 0, stream>>>(bsum, NB, N, bpre, offsets);
    scatter_k<<<(E + 255) / 256, 256, 0, stream>>>(ei, et, E, N, meta, offsets, bpre, cursor, sorted);
    rgcn_main_k<<<(N + GTILE - 1) / GTILE, 1024, 0, stream>>>(d_in[2], d_in[4], d_in[6], BT,
                                                              meta, offsets, bpre, sorted, d_out, N);
}